// Round 3
// baseline (251.513 us; speedup 1.0000x reference)
//
#include <hip/hip_runtime.h>

#define OBS_LEN 8
#define PRED_LEN 12
#define TILE_B 64
#define NTHREADS 256
#define HSTR 72  // u16 units per row; 144B => 16B-aligned, 2-way-free LDS banks

typedef __attribute__((ext_vector_type(8))) short short8;     // 8 bf16
typedef __attribute__((ext_vector_type(4))) float floatx4;
typedef __attribute__((ext_vector_type(2))) float floatx2;
typedef __attribute__((ext_vector_type(4))) unsigned short ushortx4;
typedef unsigned short u16;
typedef unsigned int u32;

// RNE bf16 round (finite inputs only)
__device__ __forceinline__ u16 f2bf(float f) {
  u32 u = __builtin_bit_cast(u32, f);
  u += 0x7fffu + ((u >> 16) & 1u);
  return (u16)(u >> 16);
}
__device__ __forceinline__ float bf2f(u16 h) {
  return __builtin_bit_cast(float, ((u32)h) << 16);
}
__device__ __forceinline__ float rndbf(float f) { return bf2f(f2bf(f)); }

#if __has_builtin(__builtin_amdgcn_exp2f)
__device__ __forceinline__ float fexp2_(float x) { return __builtin_amdgcn_exp2f(x); }
#else
__device__ __forceinline__ float fexp2_(float x) { return exp2f(x); }
#endif
// rcp + one Newton step: ~1-2 ulp, keeps activation mismatch vs np at ~2e-7
#if __has_builtin(__builtin_amdgcn_rcpf)
__device__ __forceinline__ float frcp_(float x) {
  float r = __builtin_amdgcn_rcpf(x);
  return r * (2.0f - x * r);
}
#else
__device__ __forceinline__ float frcp_(float x) { return 1.0f / x; }
#endif

#define L2E 1.442695040888963f
__device__ __forceinline__ float sigm_(float x) {
  return frcp_(1.0f + fexp2_(-x * L2E));
}
__device__ __forceinline__ float tanh_(float x) {
  return 1.0f - 2.0f * frcp_(fexp2_(x * (2.0f * L2E)) + 1.0f);
}

__device__ __forceinline__ floatx4 mfma_bf(short8 a, short8 b, floatx4 c) {
  return __builtin_amdgcn_mfma_f32_16x16x32_bf16(a, b, c, 0, 0, 0);
}

// A-operand fragments (A[m=lane&15][k=quad*8+j]) for this wave's 4 gate tiles
// (gate = t*64 + u0 + l16), weights rounded to bf16 = the ref's operand rounding.
__device__ __forceinline__ void load_afrags(const float* __restrict__ W,
                                            short8 (&af)[4][2],
                                            int u0, int q, int l16) {
#pragma unroll
  for (int t = 0; t < 4; ++t)
#pragma unroll
    for (int kf = 0; kf < 2; ++kf) {
      const float* src = W + (t * 64 + u0 + l16) * 64 + kf * 32 + q * 8;
      const floatx4 w0 = *(const floatx4*)src;
      const floatx4 w1 = *(const floatx4*)(src + 4);
      short8 a;
#pragma unroll
      for (int j = 0; j < 4; ++j) {
        a[j] = (short)f2bf(w0[j]);
        a[j + 4] = (short)f2bf(w1[j]);
      }
      af[t][kf] = a;
    }
}

// B-phase: gates = b + x@w_ih^T + h@w_hh^T (f32 accum, bf16 operands), pointwise,
// write h_{t+1} as bf16 (= ref's operand rounding of h for the next matmul).
__device__ __forceinline__ void bstep(const u16* __restrict__ rdh,
                                      const u16* __restrict__ rdx,
                                      u16* __restrict__ wrh,
                                      const short8 (&afh)[4][2],
                                      const short8 (&afx)[4][2],
                                      const float (&bv)[4][4], float (&c)[4][4],
                                      int q, int l16, int u0) {
  floatx4 acc[4][4];
#pragma unroll
  for (int n = 0; n < 4; ++n)
#pragma unroll
    for (int t = 0; t < 4; ++t)
#pragma unroll
      for (int r = 0; r < 4; ++r) acc[n][t][r] = bv[t][r];
#pragma unroll
  for (int n = 0; n < 4; ++n) {
    const int s = n * 16 + l16;
    const short8 hb0 = *(const short8*)(rdh + s * HSTR + q * 8);
    const short8 hb1 = *(const short8*)(rdh + s * HSTR + 32 + q * 8);
    const short8 xb0 = *(const short8*)(rdx + s * HSTR + q * 8);
    const short8 xb1 = *(const short8*)(rdx + s * HSTR + 32 + q * 8);
#pragma unroll
    for (int t = 0; t < 4; ++t) {
      acc[n][t] = mfma_bf(afh[t][0], hb0, acc[n][t]);
      acc[n][t] = mfma_bf(afx[t][0], xb0, acc[n][t]);
      acc[n][t] = mfma_bf(afh[t][1], hb1, acc[n][t]);
      acc[n][t] = mfma_bf(afx[t][1], xb1, acc[n][t]);
    }
  }
#pragma unroll
  for (int n = 0; n < 4; ++n) {
    const int s = n * 16 + l16;
    ushortx4 o;
#pragma unroll
    for (int r = 0; r < 4; ++r) {
      const float ig = acc[n][0][r], fg = acc[n][1][r];
      const float gg = acc[n][2][r], og = acc[n][3][r];
      const float cc = sigm_(fg) * c[n][r] + sigm_(ig) * tanh_(gg);
      c[n][r] = cc;
      const float h = sigm_(og) * tanh_(cc);
      o[r] = f2bf(h);
    }
    *(ushortx4*)(wrh + s * HSTR + u0 + q * 4) = o;
  }
}

// A-phase (encoder / dec step 0): x[s][e] = bf16( bf16(r)@bf16(emb_w)^T + emb_b )
__device__ __forceinline__ void axphase(const float* __restrict__ posrow,
                                        const float* __restrict__ ew0,
                                        const float* __restrict__ ew1,
                                        const float* __restrict__ eb,
                                        u16* __restrict__ xw, int s, int p) {
  const float r0 = rndbf(posrow[s * 2]);
  const float r1 = rndbf(posrow[s * 2 + 1]);
#pragma unroll
  for (int i4 = 0; i4 < 4; ++i4) {
    ushortx4 v;
#pragma unroll
    for (int ii = 0; ii < 4; ++ii) {
      const int e = p * 16 + i4 * 4 + ii;
      const float xe = r0 * ew0[e] + r1 * ew1[e] + eb[e];
      v[ii] = f2bf(xe);
    }
    *(ushortx4*)(xw + s * HSTR + p * 16 + i4 * 4) = v;
  }
}

// A-phase (decoder j>=1): rel_{j-1} = bf16(h_j)@bf16(h2p_w)^T + h2p_b (f32 out),
// then x_j = bf16( bf16(rel)@bf16(dec_emb_w)^T + dec_emb_b ).
__device__ __forceinline__ void areldot(const u16* __restrict__ h,
                                        const float* __restrict__ hw0,
                                        const float* __restrict__ hw1,
                                        float b2p0, float b2p1, int s, int p,
                                        float& r0, float& r1) {
  float d0 = 0.f, d1 = 0.f;
#pragma unroll
  for (int i4 = 0; i4 < 4; ++i4) {
    const ushortx4 hv4 = *(const ushortx4*)(h + s * HSTR + p * 16 + i4 * 4);
#pragma unroll
    for (int ii = 0; ii < 4; ++ii) {
      const int u = p * 16 + i4 * 4 + ii;
      const float hv = bf2f(hv4[ii]);
      d0 += hv * hw0[u];
      d1 += hv * hw1[u];
    }
  }
  d0 += __shfl_xor(d0, 1);
  d0 += __shfl_xor(d0, 2);
  d1 += __shfl_xor(d1, 1);
  d1 += __shfl_xor(d1, 2);
  r0 = d0 + b2p0;
  r1 = d1 + b2p1;
}

__global__ void __launch_bounds__(NTHREADS, 2)
lstm_kernel(const float* __restrict__ obs_rel,
            const float* __restrict__ enc_emb_w, const float* __restrict__ enc_emb_b,
            const float* __restrict__ enc_w_ih, const float* __restrict__ enc_w_hh,
            const float* __restrict__ enc_b_ih, const float* __restrict__ enc_b_hh,
            const float* __restrict__ dec_emb_w, const float* __restrict__ dec_emb_b,
            const float* __restrict__ dec_w_ih, const float* __restrict__ dec_w_hh,
            const float* __restrict__ dec_b_ih, const float* __restrict__ dec_b_hh,
            const float* __restrict__ h2p_w, const float* __restrict__ h2p_b,
            float* __restrict__ out, int batch) {
  __shared__ __align__(16) u16 hS[2][TILE_B * HSTR];
  __shared__ __align__(16) u16 xS[TILE_B * HSTR];
  __shared__ __align__(16) float posS[OBS_LEN * TILE_B * 2];
  __shared__ float ew0e[64], ew1e[64], ebe[64];
  __shared__ float ew0d[64], ew1d[64], ebd[64];
  __shared__ float hw0[64], hw1[64];

  const int tid = threadIdx.x;
  const int wv = tid >> 6, lane = tid & 63;
  const int q = lane >> 4, l16 = lane & 15;
  const int u0 = wv << 4;
  const int s = tid >> 2, p = tid & 3;
  const long S0 = (long)blockIdx.x * TILE_B;

  {  // stage the 8 encoder-step positions for this tile (coalesced float4)
    const int t = tid >> 5, i = tid & 31;
    *(floatx4*)&posS[t * (TILE_B * 2) + i * 4] =
        *(const floatx4*)(obs_rel + (long)t * batch * 2 + S0 * 2 + i * 4);
  }
  if (tid < 64) {  // emb/h2p tables: weights bf16-rounded (operands), biases f32
    ew0e[tid] = rndbf(enc_emb_w[tid * 2]);
    ew1e[tid] = rndbf(enc_emb_w[tid * 2 + 1]);
    ebe[tid] = enc_emb_b[tid];
    ew0d[tid] = rndbf(dec_emb_w[tid * 2]);
    ew1d[tid] = rndbf(dec_emb_w[tid * 2 + 1]);
    ebd[tid] = dec_emb_b[tid];
    hw0[tid] = rndbf(h2p_w[tid]);
    hw1[tid] = rndbf(h2p_w[64 + tid]);
  }
  for (int i = tid; i < TILE_B * HSTR / 2; i += NTHREADS) ((u32*)&hS[0][0])[i] = 0;

  short8 afh[4][2], afx[4][2];
  float bv[4][4], c[4][4];
  load_afrags(enc_w_hh, afh, u0, q, l16);
  load_afrags(enc_w_ih, afx, u0, q, l16);
#pragma unroll
  for (int t = 0; t < 4; ++t)
#pragma unroll
    for (int r = 0; r < 4; ++r) {
      const int g = t * 64 + u0 + q * 4 + r;
      bv[t][r] = enc_b_ih[g] + enc_b_hh[g];
      c[t][r] = 0.f;
    }
  const float b2p0 = h2p_b[0], b2p1 = h2p_b[1];
  __syncthreads();

  int pb = 0;
#pragma unroll 1
  for (int t = 0; t < OBS_LEN; ++t) {
    axphase(&posS[t * (TILE_B * 2)], ew0e, ew1e, ebe, xS, s, p);
    __syncthreads();
    bstep(hS[pb], xS, hS[pb ^ 1], afh, afx, bv, c, q, l16, u0);
    __syncthreads();
    pb ^= 1;
  }

  // ---- decoder constants; step 0 input x = emb(last_rel), c reset to 0
  load_afrags(dec_w_hh, afh, u0, q, l16);
  load_afrags(dec_w_ih, afx, u0, q, l16);
#pragma unroll
  for (int t = 0; t < 4; ++t)
#pragma unroll
    for (int r = 0; r < 4; ++r) {
      const int g = t * 64 + u0 + q * 4 + r;
      bv[t][r] = dec_b_ih[g] + dec_b_hh[g];
      c[t][r] = 0.f;
    }
  axphase(&posS[7 * (TILE_B * 2)], ew0d, ew1d, ebd, xS, s, p);
  __syncthreads();
  bstep(hS[pb], xS, hS[pb ^ 1], afh, afx, bv, c, q, l16, u0);
  __syncthreads();
  pb ^= 1;

  // ---- decoder steps 1..11: A computes rel_{j-1} (f32 out) + x_j; B advances h
#pragma unroll 1
  for (int j = 1; j < PRED_LEN; ++j) {
    float r0, r1;
    areldot(hS[pb], hw0, hw1, b2p0, b2p1, s, p, r0, r1);
    if (p == 0)
      *(floatx2*)(out + (long)(j - 1) * batch * 2 + (S0 + s) * 2) = floatx2{r0, r1};
    {
      const float rb0 = rndbf(r0), rb1 = rndbf(r1);
#pragma unroll
      for (int i4 = 0; i4 < 4; ++i4) {
        ushortx4 v;
#pragma unroll
        for (int ii = 0; ii < 4; ++ii) {
          const int e = p * 16 + i4 * 4 + ii;
          const float xe = rb0 * ew0d[e] + rb1 * ew1d[e] + ebd[e];
          v[ii] = f2bf(xe);
        }
        *(ushortx4*)(xS + s * HSTR + p * 16 + i4 * 4) = v;
      }
    }
    __syncthreads();
    bstep(hS[pb], xS, hS[pb ^ 1], afh, afx, bv, c, q, l16, u0);
    __syncthreads();
    pb ^= 1;
  }

  // ---- trailing output: rel_pos[11] from h_12
  {
    float r0, r1;
    areldot(hS[pb], hw0, hw1, b2p0, b2p1, s, p, r0, r1);
    if (p == 0)
      *(floatx2*)(out + (long)(PRED_LEN - 1) * batch * 2 + (S0 + s) * 2) =
          floatx2{r0, r1};
  }
}

extern "C" void kernel_launch(void* const* d_in, const int* in_sizes, int n_in,
                              void* d_out, int out_size, void* d_ws, size_t ws_size,
                              hipStream_t stream) {
  const float* obs_rel = (const float*)d_in[1];
  const int batch = in_sizes[1] / (OBS_LEN * 2);  // 65536

  const int blocks = batch / TILE_B;  // 1024
  hipLaunchKernelGGL(lstm_kernel, dim3(blocks), dim3(NTHREADS), 0, stream,
                     obs_rel,
                     (const float*)d_in[2], (const float*)d_in[3],
                     (const float*)d_in[4], (const float*)d_in[5],
                     (const float*)d_in[6], (const float*)d_in[7],
                     (const float*)d_in[8], (const float*)d_in[9],
                     (const float*)d_in[10], (const float*)d_in[11],
                     (const float*)d_in[12], (const float*)d_in[13],
                     (const float*)d_in[14], (const float*)d_in[15],
                     (float*)d_out, batch);
}

// Round 4
// 240.454 us; speedup vs baseline: 1.0460x; 1.0460x over previous
//
#include <hip/hip_runtime.h>

#define OBS_LEN 8
#define PRED_LEN 12
#define TILE_B 64
#define NTHREADS 256
#define HSTR 72  // u16 units per row; 144B => 16B-aligned, 2-way-free LDS banks

typedef __attribute__((ext_vector_type(8))) short short8;  // 8 bf16
typedef __attribute__((ext_vector_type(4))) float floatx4;
typedef __attribute__((ext_vector_type(2))) float floatx2;
typedef __attribute__((ext_vector_type(4))) unsigned short ushortx4;
typedef unsigned short u16;
typedef unsigned int u32;

// HW bf16 round (RNE, v_cvt_pk_bf16_f32 on gfx950; sw fallback is also RNE)
__device__ __forceinline__ u16 f2bf(float f) {
  __bf16 b = (__bf16)f;
  return __builtin_bit_cast(u16, b);
}
__device__ __forceinline__ float bf2f(u16 h) {
  return __builtin_bit_cast(float, ((u32)h) << 16);
}
__device__ __forceinline__ float rndbf(float f) { return (float)(__bf16)f; }

#if __has_builtin(__builtin_amdgcn_exp2f)
__device__ __forceinline__ float fexp2_(float x) { return __builtin_amdgcn_exp2f(x); }
#else
__device__ __forceinline__ float fexp2_(float x) { return exp2f(x); }
#endif
#if __has_builtin(__builtin_amdgcn_rcpf)
__device__ __forceinline__ float rcp_nr(float x) {  // ~0.5ulp
  float r = __builtin_amdgcn_rcpf(x);
  return r * (2.0f - x * r);
}
#else
__device__ __forceinline__ float rcp_nr(float x) { return 1.0f / x; }
#endif

#define L2E 1.442695040888963f

__device__ __forceinline__ floatx4 mfma_bf(short8 a, short8 b, floatx4 c) {
  return __builtin_amdgcn_mfma_f32_16x16x32_bf16(a, b, c, 0, 0, 0);
}

// A-operand fragments (A[m=lane&15][k=quad*8+j]) for this wave's 4 gate tiles
// (gate = t*64 + u0 + l16), weights rounded to bf16 = the ref's operand rounding.
__device__ __forceinline__ void load_afrags(const float* __restrict__ W,
                                            short8 (&af)[4][2],
                                            int u0, int q, int l16) {
#pragma unroll
  for (int t = 0; t < 4; ++t)
#pragma unroll
    for (int kf = 0; kf < 2; ++kf) {
      const float* src = W + (t * 64 + u0 + l16) * 64 + kf * 32 + q * 8;
      const floatx4 w0 = *(const floatx4*)src;
      const floatx4 w1 = *(const floatx4*)(src + 4);
      short8 a;
#pragma unroll
      for (int j = 0; j < 4; ++j) {
        a[j] = (short)f2bf(w0[j]);
        a[j + 4] = (short)f2bf(w1[j]);
      }
      af[t][kf] = a;
    }
}

// h-half of the step: acc = bias + h@w_hh^T (f32 accum, bf16 operands)
__device__ __forceinline__ void bstep_h(const u16* __restrict__ rdh,
                                        const short8 (&afh)[4][2],
                                        const float (&bv)[4][4],
                                        floatx4 (&acc)[4][4], int q, int l16) {
#pragma unroll
  for (int n = 0; n < 4; ++n)
#pragma unroll
    for (int t = 0; t < 4; ++t)
#pragma unroll
      for (int r = 0; r < 4; ++r) acc[n][t][r] = bv[t][r];
#pragma unroll
  for (int n = 0; n < 4; ++n) {
    const int s = n * 16 + l16;
    const short8 hb0 = *(const short8*)(rdh + s * HSTR + q * 8);
    const short8 hb1 = *(const short8*)(rdh + s * HSTR + 32 + q * 8);
#pragma unroll
    for (int t = 0; t < 4; ++t) {
      acc[n][t] = mfma_bf(afh[t][0], hb0, acc[n][t]);
      acc[n][t] = mfma_bf(afh[t][1], hb1, acc[n][t]);
    }
  }
}

// x-half + pointwise (shared-denominator activations) + bf16 h write
__device__ __forceinline__ void bstep_x(const u16* __restrict__ rdx,
                                        u16* __restrict__ wrh,
                                        const short8 (&afx)[4][2],
                                        floatx4 (&acc)[4][4], float (&c)[4][4],
                                        int q, int l16, int u0) {
#pragma unroll
  for (int n = 0; n < 4; ++n) {
    const int s = n * 16 + l16;
    const short8 xb0 = *(const short8*)(rdx + s * HSTR + q * 8);
    const short8 xb1 = *(const short8*)(rdx + s * HSTR + 32 + q * 8);
#pragma unroll
    for (int t = 0; t < 4; ++t) {
      acc[n][t] = mfma_bf(afx[t][0], xb0, acc[n][t]);
      acc[n][t] = mfma_bf(afx[t][1], xb1, acc[n][t]);
    }
  }
#pragma unroll
  for (int n = 0; n < 4; ++n) {
    const int s = n * 16 + l16;
    ushortx4 o;
#pragma unroll
    for (int r = 0; r < 4; ++r) {
      const float ig = acc[n][0][r], fg = acc[n][1][r];
      const float gg = acc[n][2][r], og = acc[n][3][r];
      const float ei = fexp2_(ig * -L2E);
      const float ef = fexp2_(fg * -L2E);
      const float eg = fexp2_(gg * (2.0f * L2E));
      const float eo = fexp2_(og * -L2E);
      const float A = 1.0f + ei;      // 1/sig(i)
      const float Bg = eg + 1.0f;     // tanh(g) = (eg-1)/Bg
      const float F = 1.0f + ef;      // 1/sig(f)
      const float P = A * Bg;
      const float cc = (c[n][r] * P + (eg - 1.0f) * F) * rcp_nr(F * P);
      c[n][r] = cc;
      const float ec = fexp2_(cc * (2.0f * L2E));
      const float h = (ec - 1.0f) * rcp_nr((1.0f + eo) * (ec + 1.0f));
      o[r] = f2bf(h);
    }
    *(ushortx4*)(wrh + s * HSTR + u0 + q * 4) = o;
  }
}

// x[s][e] = bf16( bf16(r)@bf16(emb_w)^T + emb_b ), thread (s4,p4) does 16 e's
__device__ __forceinline__ void axphase(const float* __restrict__ orow,
                                        const float* __restrict__ ew0,
                                        const float* __restrict__ ew1,
                                        const float* __restrict__ eb,
                                        u16* __restrict__ xw, int s, int p) {
  const floatx2 rr = *(const floatx2*)(orow + s * 2);
  const float r0 = rndbf(rr.x);
  const float r1 = rndbf(rr.y);
#pragma unroll
  for (int i4 = 0; i4 < 4; ++i4) {
    ushortx4 v;
#pragma unroll
    for (int ii = 0; ii < 4; ++ii) {
      const int e = p * 16 + i4 * 4 + ii;
      const float xe = r0 * ew0[e] + r1 * ew1[e] + eb[e];
      v[ii] = f2bf(xe);
    }
    *(ushortx4*)(xw + s * HSTR + p * 16 + i4 * 4) = v;
  }
}

// rel = bf16(h)@bf16(h2p_w)^T + h2p_b, f32; 4 threads/sample, shfl reduce
__device__ __forceinline__ void areldot(const u16* __restrict__ h,
                                        const float* __restrict__ hw0,
                                        const float* __restrict__ hw1,
                                        float b2p0, float b2p1, int s, int p,
                                        float& r0, float& r1) {
  float d0 = 0.f, d1 = 0.f;
#pragma unroll
  for (int i4 = 0; i4 < 4; ++i4) {
    const ushortx4 hv4 = *(const ushortx4*)(h + s * HSTR + p * 16 + i4 * 4);
#pragma unroll
    for (int ii = 0; ii < 4; ++ii) {
      const int u = p * 16 + i4 * 4 + ii;
      const float hv = bf2f(hv4[ii]);
      d0 += hv * hw0[u];
      d1 += hv * hw1[u];
    }
  }
  d0 += __shfl_xor(d0, 1);
  d0 += __shfl_xor(d0, 2);
  d1 += __shfl_xor(d1, 1);
  d1 += __shfl_xor(d1, 2);
  r0 = d0 + b2p0;
  r1 = d1 + b2p1;
}

__global__ void __launch_bounds__(NTHREADS, 2)
lstm_kernel(const float* __restrict__ obs_rel,
            const float* __restrict__ enc_emb_w, const float* __restrict__ enc_emb_b,
            const float* __restrict__ enc_w_ih, const float* __restrict__ enc_w_hh,
            const float* __restrict__ enc_b_ih, const float* __restrict__ enc_b_hh,
            const float* __restrict__ dec_emb_w, const float* __restrict__ dec_emb_b,
            const float* __restrict__ dec_w_ih, const float* __restrict__ dec_w_hh,
            const float* __restrict__ dec_b_ih, const float* __restrict__ dec_b_hh,
            const float* __restrict__ h2p_w, const float* __restrict__ h2p_b,
            float* __restrict__ out, int batch) {
  __shared__ __align__(16) u16 hS[2][TILE_B * HSTR];
  __shared__ __align__(16) u16 xS[2][TILE_B * HSTR];
  __shared__ float ew0e[64], ew1e[64], ebe[64];
  __shared__ float ew0d[64], ew1d[64], ebd[64];
  __shared__ float hw0[64], hw1[64];

  const int tid = threadIdx.x;
  const int wv = tid >> 6, lane = tid & 63;
  const int q = lane >> 4, l16 = lane & 15;
  const int u0 = wv << 4;
  const int s4 = tid >> 2, p4 = tid & 3;
  const long S0 = (long)blockIdx.x * TILE_B;

  if (tid < 64) {  // emb/h2p tables: weights bf16-rounded (operands), biases f32
    ew0e[tid] = rndbf(enc_emb_w[tid * 2]);
    ew1e[tid] = rndbf(enc_emb_w[tid * 2 + 1]);
    ebe[tid] = enc_emb_b[tid];
    ew0d[tid] = rndbf(dec_emb_w[tid * 2]);
    ew1d[tid] = rndbf(dec_emb_w[tid * 2 + 1]);
    ebd[tid] = dec_emb_b[tid];
    hw0[tid] = rndbf(h2p_w[tid]);
    hw1[tid] = rndbf(h2p_w[64 + tid]);
  }
  for (int i = tid; i < TILE_B * HSTR / 2; i += NTHREADS) ((u32*)&hS[0][0])[i] = 0;

  short8 afh[4][2], afx[4][2];
  floatx4 acc[4][4];
  float bv[4][4], c[4][4];
  load_afrags(enc_w_hh, afh, u0, q, l16);
  load_afrags(enc_w_ih, afx, u0, q, l16);
#pragma unroll
  for (int t = 0; t < 4; ++t)
#pragma unroll
    for (int r = 0; r < 4; ++r) {
      const int g = t * 64 + u0 + q * 4 + r;
      bv[t][r] = enc_b_ih[g] + enc_b_hh[g];
      c[t][r] = 0.f;
    }
  const float b2p0 = h2p_b[0], b2p1 = h2p_b[1];
  __syncthreads();  // tables + h0 visible
  axphase(obs_rel + S0 * 2, ew0e, ew1e, ebe, xS[0], s4, p4);
  __syncthreads();  // x(0) visible

  int pb = 0;
#pragma unroll 1
  for (int t = 0; t < OBS_LEN; ++t) {
    // produce x(t+1) into the other buffer (independent of h -> overlaps MFMA);
    // t==7 produces the decoder step-0 input with dec tables into xS[0]
    const int tn = t + 1;
    const float* orow = obs_rel + (long)((tn < 8) ? tn : 7) * batch * 2 + S0 * 2;
    if (tn < 8)
      axphase(orow, ew0e, ew1e, ebe, xS[tn & 1], s4, p4);
    else
      axphase(orow, ew0d, ew1d, ebd, xS[0], s4, p4);
    bstep_h(hS[pb], afh, bv, acc, q, l16);
    bstep_x(xS[t & 1], hS[pb ^ 1], afx, acc, c, q, l16, u0);
    __syncthreads();
    pb ^= 1;
  }

  // ---- decoder weights; step 0 (x already staged in xS[0]), c reset to 0
  load_afrags(dec_w_hh, afh, u0, q, l16);
  load_afrags(dec_w_ih, afx, u0, q, l16);
#pragma unroll
  for (int t = 0; t < 4; ++t)
#pragma unroll
    for (int r = 0; r < 4; ++r) {
      const int g = t * 64 + u0 + q * 4 + r;
      bv[t][r] = dec_b_ih[g] + dec_b_hh[g];
      c[t][r] = 0.f;
    }
  bstep_h(hS[pb], afh, bv, acc, q, l16);
  bstep_x(xS[0], hS[pb ^ 1], afx, acc, c, q, l16, u0);
  __syncthreads();
  pb ^= 1;

  // ---- decoder steps 1..11: I1 = rel+xgen+out + h-MFMAs (overlap), I2 = rest
#pragma unroll 1
  for (int j = 1; j < PRED_LEN; ++j) {
    float r0, r1;
    areldot(hS[pb], hw0, hw1, b2p0, b2p1, s4, p4, r0, r1);
    if (p4 == 0)
      *(floatx2*)(out + (long)(j - 1) * batch * 2 + (S0 + s4) * 2) = floatx2{r0, r1};
    {
      const float rb0 = rndbf(r0), rb1 = rndbf(r1);
#pragma unroll
      for (int i4 = 0; i4 < 4; ++i4) {
        ushortx4 v;
#pragma unroll
        for (int ii = 0; ii < 4; ++ii) {
          const int e = p4 * 16 + i4 * 4 + ii;
          const float xe = rb0 * ew0d[e] + rb1 * ew1d[e] + ebd[e];
          v[ii] = f2bf(xe);
        }
        *(ushortx4*)(&xS[0][0] + s4 * HSTR + p4 * 16 + i4 * 4) = v;
      }
    }
    bstep_h(hS[pb], afh, bv, acc, q, l16);
    __syncthreads();
    bstep_x(xS[0], hS[pb ^ 1], afx, acc, c, q, l16, u0);
    __syncthreads();
    pb ^= 1;
  }

  // ---- trailing output: rel_pos[11] from h_12
  {
    float r0, r1;
    areldot(hS[pb], hw0, hw1, b2p0, b2p1, s4, p4, r0, r1);
    if (p4 == 0)
      *(floatx2*)(out + (long)(PRED_LEN - 1) * batch * 2 + (S0 + s4) * 2) =
          floatx2{r0, r1};
  }
}

extern "C" void kernel_launch(void* const* d_in, const int* in_sizes, int n_in,
                              void* d_out, int out_size, void* d_ws, size_t ws_size,
                              hipStream_t stream) {
  const float* obs_rel = (const float*)d_in[1];
  const int batch = in_sizes[1] / (OBS_LEN * 2);  // 65536

  const int blocks = batch / TILE_B;  // 1024
  hipLaunchKernelGGL(lstm_kernel, dim3(blocks), dim3(NTHREADS), 0, stream,
                     obs_rel,
                     (const float*)d_in[2], (const float*)d_in[3],
                     (const float*)d_in[4], (const float*)d_in[5],
                     (const float*)d_in[6], (const float*)d_in[7],
                     (const float*)d_in[8], (const float*)d_in[9],
                     (const float*)d_in[10], (const float*)d_in[11],
                     (const float*)d_in[12], (const float*)d_in[13],
                     (const float*)d_in[14], (const float*)d_in[15],
                     (float*)d_out, batch);
}